// Round 1
// baseline (158.362 us; speedup 1.0000x reference)
//
#include <hip/hip_runtime.h>
#include <math.h>

// GAT layer: B=16, N=1024, IN=128, H=2, D=64. All fp32.
// out = elu( softmax_m(leakyrelu(e_src[n]+e_dst[m])) @ hp + h )
//
// Kernel A: hp = h @ Wcat (Wcat[i][h*64+d] = W[h][i][d]); e_src/e_dst fused.
// Kernel B: per (b,h,ntile): flash-style attention. Row max is closed-form:
//   max_m f(s_n+d_m) = f(s_n + dmax) since leakyrelu is monotonic.

#define GAT_ALPHA 0.2f

__device__ __forceinline__ float leaky(float x) {
    return x >= 0.0f ? x : GAT_ALPHA * x;
}

// ---------------------------------------------------------------------------
// Kernel A: 256 blocks x 256 threads. Block = 64 rows x 128 cols.
// ---------------------------------------------------------------------------
__global__ __launch_bounds__(256) void gat_hp(
    const float* __restrict__ hg,   // (16384, 128)
    const float* __restrict__ Wg,   // (2, 128, 64)
    const float* __restrict__ ag,   // (2, 128)
    float* __restrict__ hp,         // (16384, 128) ws
    float* __restrict__ es_g,       // (32, 1024) ws
    float* __restrict__ ed_g)       // (32, 1024) ws
{
    __shared__ float Ws[32 * 128];   // 16 KB: W chunk [ii][c]
    __shared__ float hts[32 * 64];   // 8 KB: h chunk transposed [ii][row]
    __shared__ float a_s[256];       // a_src_cat[0..127], a_dst_cat[128..255]

    const int t = threadIdx.x;
    const int bn0 = blockIdx.x * 64;       // global row base (bn index)
    const int b = bn0 >> 10;
    const int nloc = bn0 & 1023;

    if (t < 128) {
        int hh = t >> 6, d = t & 63;
        a_s[t]       = ag[hh * 128 + d];        // a_src
        a_s[128 + t] = ag[hh * 128 + 64 + d];   // a_dst
    }

    const int tx = t & 31;    // cols tx*4..tx*4+3
    const int ty = t >> 5;    // rows ty*8..ty*8+7

    float acc[8][4];
#pragma unroll
    for (int r = 0; r < 8; ++r)
#pragma unroll
        for (int j = 0; j < 4; ++j) acc[r][j] = 0.0f;

    for (int kc = 0; kc < 4; ++kc) {
        const int i0 = kc * 32;
        __syncthreads();
        // stage W chunk: Ws[ii*128 + c] = W[c/64][i0+ii][c%64]
#pragma unroll
        for (int k = 0; k < 4; ++k) {
            int idx = t + k * 256;            // float4 index, 1024 total
            int ii = idx >> 5;
            int c  = (idx & 31) << 2;
            int hh = c >> 6, d = c & 63;
            float4 v = *(const float4*)(Wg + (hh * 128 + i0 + ii) * 64 + d);
            *(float4*)(&Ws[ii * 128 + c]) = v;
        }
        // stage h chunk transposed: hts[ii*64 + r] = h[bn0+r][i0+ii]
#pragma unroll
        for (int k = 0; k < 2; ++k) {
            int idx = t + k * 256;            // float4 index, 512 total
            int r  = idx >> 3;
            int iq = idx & 7;
            float4 v = *(const float4*)(hg + (size_t)(bn0 + r) * 128 + i0 + iq * 4);
            hts[(iq * 4 + 0) * 64 + r] = v.x;
            hts[(iq * 4 + 1) * 64 + r] = v.y;
            hts[(iq * 4 + 2) * 64 + r] = v.z;
            hts[(iq * 4 + 3) * 64 + r] = v.w;
        }
        __syncthreads();
#pragma unroll
        for (int i = 0; i < 32; ++i) {
            float4 wv = *(const float4*)(&Ws[i * 128 + tx * 4]);
            float4 h0 = *(const float4*)(&hts[i * 64 + ty * 8]);
            float4 h1 = *(const float4*)(&hts[i * 64 + ty * 8 + 4]);
            float hr[8] = {h0.x, h0.y, h0.z, h0.w, h1.x, h1.y, h1.z, h1.w};
            float wj[4] = {wv.x, wv.y, wv.z, wv.w};
#pragma unroll
            for (int r = 0; r < 8; ++r)
#pragma unroll
                for (int j = 0; j < 4; ++j)
                    acc[r][j] = fmaf(hr[r], wj[j], acc[r][j]);
        }
    }

    // write hp
#pragma unroll
    for (int r = 0; r < 8; ++r) {
        float4 v = {acc[r][0], acc[r][1], acc[r][2], acc[r][3]};
        *(float4*)(hp + (size_t)(bn0 + ty * 8 + r) * 128 + tx * 4) = v;
    }

    // e_src / e_dst: dot each hp row (per head) with a_src/a_dst
    float es[8], ed[8];
#pragma unroll
    for (int r = 0; r < 8; ++r) {
        float s = 0.0f, dd = 0.0f;
#pragma unroll
        for (int j = 0; j < 4; ++j) {
            s  = fmaf(acc[r][j], a_s[tx * 4 + j], s);
            dd = fmaf(acc[r][j], a_s[128 + tx * 4 + j], dd);
        }
        es[r] = s; ed[r] = dd;
    }
    // reduce across the 16 tx-groups of each head (tx 0..15 = head0, 16..31 = head1)
#pragma unroll
    for (int off = 1; off <= 8; off <<= 1) {
#pragma unroll
        for (int r = 0; r < 8; ++r) {
            es[r] += __shfl_xor(es[r], off, 64);
            ed[r] += __shfl_xor(ed[r], off, 64);
        }
    }
    if ((tx & 15) == 0) {
        int hh = tx >> 4;
        size_t base = (size_t)(b * 2 + hh) * 1024 + nloc + ty * 8;
#pragma unroll
        for (int r = 0; r < 8; ++r) {
            es_g[base + r] = es[r];
            ed_g[base + r] = ed[r];
        }
    }
}

// ---------------------------------------------------------------------------
// Kernel B: 256 blocks x 256 threads. Block = one (b, h, 128-row n-tile).
// ---------------------------------------------------------------------------
__global__ __launch_bounds__(256) void gat_attn(
    const float* __restrict__ hg,     // (16384, 128)
    const float* __restrict__ hp,     // (16384, 128)
    const float* __restrict__ es_g,   // (32, 1024)
    const float* __restrict__ ed_g,   // (32, 1024)
    float* __restrict__ out)          // (16384, 128)
{
    __shared__ float hp_s[64 * 64];    // 16 KB: hp chunk [m][d]
    __shared__ float Pt_s[64 * 128];   // 32 KB: P transposed [m][n]
    __shared__ float ed_s[1024];       // 4 KB: full e_dst row for this (b,h)
    __shared__ float l_s[128];
    __shared__ float lpart[2 * 128];
    __shared__ float wmax[4];

    const int t = threadIdx.x;
    const int blk = blockIdx.x;
    const int bh = blk >> 3;          // 0..31
    const int nt = blk & 7;
    const int b  = bh >> 1;
    const int hh = bh & 1;
    const int n0 = nt * 128;

    // stage e_dst + block-wide max (dmax)
    {
        float4 v = *(const float4*)(ed_g + (size_t)bh * 1024 + t * 4);
        *(float4*)(&ed_s[t * 4]) = v;
        float mx = fmaxf(fmaxf(v.x, v.y), fmaxf(v.z, v.w));
#pragma unroll
        for (int off = 1; off < 64; off <<= 1) mx = fmaxf(mx, __shfl_xor(mx, off, 64));
        if ((t & 63) == 0) wmax[t >> 6] = mx;
    }
    __syncthreads();
    const float dmax = fmaxf(fmaxf(wmax[0], wmax[1]), fmaxf(wmax[2], wmax[3]));

    // P-compute mapping: thread -> (row nn, m-quarter mq)
    const int nn = t & 127;
    const int mq = t >> 7;
    const float s = es_g[(size_t)bh * 1024 + n0 + nn];
    const float M = leaky(s + dmax);       // true row max of f (f monotonic)
    float lsum = 0.0f;

    // matmul mapping: thread -> (4 cols tx*4, 8 rows ty*8)
    const int tx = t & 15;
    const int ty = t >> 4;

    float acc[8][4];
#pragma unroll
    for (int r = 0; r < 8; ++r)
#pragma unroll
        for (int j = 0; j < 4; ++j) acc[r][j] = 0.0f;

    for (int mc = 0; mc < 16; ++mc) {
        const int m0 = mc * 64;
        __syncthreads();   // protect prev chunk's LDS from overwrite
        // stage hp chunk: hp_s[row*64 + d] = hp[b, m0+row, hh, d]
#pragma unroll
        for (int k = 0; k < 4; ++k) {
            int idx = t + k * 256;            // float4 index, 1024 total
            int row = idx >> 4;
            int dq  = (idx & 15) * 4;
            float4 v = *(const float4*)(hp +
                (size_t)((b * 1024 + m0 + row) * 2 + hh) * 64 + dq);
            *(float4*)(&hp_s[row * 64 + dq]) = v;
        }
        // compute P tile (transposed): Pt[m][n] = exp(f(s_n + d_m) - M_n)
#pragma unroll
        for (int k = 0; k < 32; ++k) {
            int m = mq * 32 + k;
            float d = ed_s[m0 + m];
            float p = __expf(leaky(s + d) - M);
            Pt_s[m * 128 + nn] = p;
            lsum += p;
        }
        __syncthreads();
        // matmul: acc[r][j] += P[n][m] * hp[m][d]
#pragma unroll 2
        for (int m = 0; m < 64; ++m) {
            float4 hv = *(const float4*)(&hp_s[m * 64 + tx * 4]);
            float4 p0 = *(const float4*)(&Pt_s[m * 128 + ty * 8]);
            float4 p1 = *(const float4*)(&Pt_s[m * 128 + ty * 8 + 4]);
            float pr[8] = {p0.x, p0.y, p0.z, p0.w, p1.x, p1.y, p1.z, p1.w};
            float hj[4] = {hv.x, hv.y, hv.z, hv.w};
#pragma unroll
            for (int r = 0; r < 8; ++r)
#pragma unroll
                for (int j = 0; j < 4; ++j)
                    acc[r][j] = fmaf(pr[r], hj[j], acc[r][j]);
        }
    }

    // combine softmax denominators
    lpart[mq * 128 + nn] = lsum;
    __syncthreads();
    if (t < 128) l_s[t] = lpart[t] + lpart[128 + t];
    __syncthreads();

    // epilogue: out = elu(acc/l + h)
#pragma unroll
    for (int r = 0; r < 8; ++r) {
        int n = n0 + ty * 8 + r;
        float inv = 1.0f / l_s[ty * 8 + r];
        size_t off = (size_t)(b * 1024 + n) * 128 + hh * 64 + tx * 4;
        float4 hv = *(const float4*)(hg + off);
        float v[4];
        v[0] = acc[r][0] * inv + hv.x;
        v[1] = acc[r][1] * inv + hv.y;
        v[2] = acc[r][2] * inv + hv.z;
        v[3] = acc[r][3] * inv + hv.w;
#pragma unroll
        for (int j = 0; j < 4; ++j)
            v[j] = v[j] > 0.0f ? v[j] : (__expf(v[j]) - 1.0f);
        float4 o = {v[0], v[1], v[2], v[3]};
        *(float4*)(out + off) = o;
    }
}

// ---------------------------------------------------------------------------
extern "C" void kernel_launch(void* const* d_in, const int* in_sizes, int n_in,
                              void* d_out, int out_size, void* d_ws, size_t ws_size,
                              hipStream_t stream) {
    const float* h = (const float*)d_in[0];   // (16,1024,128)
    const float* W = (const float*)d_in[1];   // (2,128,64)
    const float* a = (const float*)d_in[2];   // (2,128,1)
    float* out = (float*)d_out;               // (16,1024,128)

    float* hp = (float*)d_ws;                 // 16384*128 floats = 8 MB
    float* es = hp + 16384 * 128;             // 32*1024
    float* ed = es + 32 * 1024;               // 32*1024

    gat_hp<<<256, 256, 0, stream>>>(h, W, a, hp, es, ed);
    gat_attn<<<256, 256, 0, stream>>>(h, hp, es, ed, out);
}

// Round 2
// 89.570 us; speedup vs baseline: 1.7680x; 1.7680x over previous
//
#include <hip/hip_runtime.h>
#include <math.h>

// GAT layer, MFMA restructure. B=16, N=1024, IN=128, H=2, D=64.
// out = elu( softmax_m(leakyrelu(e_src[n]+e_dst[m])) @ hp + h )
//
// prep:  Wp[k/8][c][k%8] bf16 (B-frag-packed W), acat = [a_src_cat | a_dst_cat]
// gat_hp: hp = h @ Wcat via mfma_16x16x32_bf16; writes hpB[bh][m/8][d][m%8] bf16
//         + es/ed (fp32) fused from the fp32 accumulators.
// gat_attn: per wave = (bh, 16-row tile). P computed in registers:
//         P = 2^( max(x,0.2x) - M ),  x = (s_n+d_m)*log2e,  M = L(s_n'+dmax').
//         No LDS, no __syncthreads anywhere: B-frags are 16B global loads from
//         hpB, L1/L2-resident (4KB active tile per bh, shared by all waves).

#define LOG2E 1.44269504088896340736f

typedef __bf16 bf16x8 __attribute__((ext_vector_type(8)));
typedef float floatx4 __attribute__((ext_vector_type(4)));

union U16x8 { uint4 u; bf16x8 b; };

__device__ __forceinline__ unsigned short f2bf(float f) {
    union { __bf16 b; unsigned short u; } x;
    x.b = (__bf16)f;
    return x.u;
}

// ---------------------------------------------------------------------------
// prep: pack W to bf16 k-major-8 layout; build acat.
// ---------------------------------------------------------------------------
__global__ __launch_bounds__(256) void gat_prep(
    const float* __restrict__ Wg,   // (2,128,64)
    const float* __restrict__ ag,   // (2,128)
    unsigned short* __restrict__ Wp,  // (16,128,8) bf16
    float* __restrict__ acat)         // (256)
{
    const int t = threadIdx.x;
#pragma unroll
    for (int i = 0; i < 64; ++i) {
        int idx = i * 256 + t;           // 16384
        int c = idx & 127, k = idx >> 7;
        float v = Wg[(c >> 6) * 8192 + k * 64 + (c & 63)];
        Wp[((k >> 3) * 128 + c) * 8 + (k & 7)] = f2bf(v);
    }
    if (t < 128) {
        acat[t]       = ag[(t >> 6) * 128 + (t & 63)];
        acat[128 + t] = ag[(t >> 6) * 128 + 64 + (t & 63)];
    }
}

// ---------------------------------------------------------------------------
// Kernel A: hp = h @ Wcat. 512 blocks x 256 thr; wave = (16-row tile, head).
// ---------------------------------------------------------------------------
__global__ __launch_bounds__(256) void gat_hp(
    const float* __restrict__ hg,        // (16384,128)
    const unsigned short* __restrict__ Wp,
    const float* __restrict__ acat,
    unsigned short* __restrict__ hpB,    // (32,128,64,8) bf16
    float* __restrict__ es_g,            // (32,1024)
    float* __restrict__ ed_g)            // (32,1024)
{
    const int t = threadIdx.x;
    const int lane = t & 63;
    const int wv = blockIdx.x * 4 + (t >> 6);   // 0..2047
    const int rt = wv >> 1;                     // global 16-row tile, 0..1023
    const int half = wv & 1;                    // head
    const int n0 = rt * 16;
    const int col = lane & 15, quad = lane >> 4;

    floatx4 acc[4];
#pragma unroll
    for (int ct = 0; ct < 4; ++ct) acc[ct] = (floatx4){0.f, 0.f, 0.f, 0.f};

    const float* hrow = hg + (size_t)(n0 + col) * 128;
    const uint4* wp4 = (const uint4*)Wp;
#pragma unroll
    for (int kq = 0; kq < 4; ++kq) {
        float4 h0 = *(const float4*)(hrow + kq * 32 + quad * 8);
        float4 h1 = *(const float4*)(hrow + kq * 32 + quad * 8 + 4);
        bf16x8 af;
        af[0] = (__bf16)h0.x; af[1] = (__bf16)h0.y;
        af[2] = (__bf16)h0.z; af[3] = (__bf16)h0.w;
        af[4] = (__bf16)h1.x; af[5] = (__bf16)h1.y;
        af[6] = (__bf16)h1.z; af[7] = (__bf16)h1.w;
        const uint4* wbase = wp4 + (size_t)(kq * 4 + quad) * 128 + half * 64;
#pragma unroll
        for (int ct = 0; ct < 4; ++ct) {
            U16x8 bu; bu.u = wbase[ct * 16 + col];
            acc[ct] = __builtin_amdgcn_mfma_f32_16x16x32_bf16(af, bu.b, acc[ct], 0, 0, 0);
        }
    }

    const int b = n0 >> 10;
    const int nloc = n0 & 1023;
    const int bh = b * 2 + half;

    // fused e_src / e_dst from fp32 accumulators
    float esr[4] = {0.f, 0.f, 0.f, 0.f}, edr[4] = {0.f, 0.f, 0.f, 0.f};
#pragma unroll
    for (int ct = 0; ct < 4; ++ct) {
        int c = half * 64 + ct * 16 + col;
        float as = acat[c], ad = acat[128 + c];
#pragma unroll
        for (int r = 0; r < 4; ++r) {
            esr[r] = fmaf(acc[ct][r], as, esr[r]);
            edr[r] = fmaf(acc[ct][r], ad, edr[r]);
        }
    }
#pragma unroll
    for (int off = 1; off <= 8; off <<= 1) {
#pragma unroll
        for (int r = 0; r < 4; ++r) {
            esr[r] += __shfl_xor(esr[r], off, 64);
            edr[r] += __shfl_xor(edr[r], off, 64);
        }
    }
    if (col == 0) {
        size_t base = (size_t)bh * 1024 + nloc + quad * 4;
#pragma unroll
        for (int r = 0; r < 4; ++r) {
            es_g[base + r] = esr[r];
            ed_g[base + r] = edr[r];
        }
    }

    // hpB stores: rows n = n0 + quad*4 + r; n%8 = (quad&1)*4 + r (4 consecutive)
    const int gloc = (nloc >> 3) + (quad >> 1);
#pragma unroll
    for (int ct = 0; ct < 4; ++ct) {
        int d = ct * 16 + col;
        uint2 pk;
        pk.x = (unsigned)f2bf(acc[ct][0]) | ((unsigned)f2bf(acc[ct][1]) << 16);
        pk.y = (unsigned)f2bf(acc[ct][2]) | ((unsigned)f2bf(acc[ct][3]) << 16);
        size_t idx = ((size_t)(bh * 128 + gloc) * 64 + d) * 8 + (quad & 1) * 4;
        *(uint2*)(hpB + idx) = pk;
    }
}

// ---------------------------------------------------------------------------
// Kernel B: attention. 512 blocks x 256 thr; wave = (bh, 16-row tile).
// blockIdx: bh = blk & 31 (XCD swizzle: same bh -> same XCD), nt = blk >> 5.
// ---------------------------------------------------------------------------
__global__ __launch_bounds__(256) void gat_attn(
    const float* __restrict__ hg,
    const unsigned short* __restrict__ hpB,
    const float* __restrict__ es_g,
    const float* __restrict__ ed_g,
    float* __restrict__ out)
{
    const int t = threadIdx.x;
    const int lane = t & 63;
    const int w = t >> 6;
    const int bh = blockIdx.x & 31;
    const int nt = blockIdx.x >> 5;
    const int b = bh >> 1, hh = bh & 1;
    const int rt = nt * 4 + w;           // 0..63
    const int n0 = rt * 16;
    const int col = lane & 15, quad = lane >> 4;

    const float* edrow = ed_g + (size_t)bh * 1024;

    // dmax over full row (per-wave, no LDS)
    float mx = -1e30f;
#pragma unroll
    for (int i = 0; i < 4; ++i) {
        float4 v = *(const float4*)(edrow + lane * 16 + i * 4);
        mx = fmaxf(mx, fmaxf(fmaxf(v.x, v.y), fmaxf(v.z, v.w)));
    }
#pragma unroll
    for (int off = 1; off < 64; off <<= 1) mx = fmaxf(mx, __shfl_xor(mx, off, 64));

    const float s2 = es_g[(size_t)bh * 1024 + n0 + col] * LOG2E;
    const float x0 = s2 + mx * LOG2E;
    const float M = fmaxf(x0, 0.2f * x0);        // row max (log2 domain)
    const float s2m = s2 - M;                    // for x >= 0 branch
    const float s5m = 0.2f * s2 - M;             // for x < 0 branch
    const float K = LOG2E, K5 = 0.2f * LOG2E;

    floatx4 acc[4];
#pragma unroll
    for (int ct = 0; ct < 4; ++ct) acc[ct] = (floatx4){0.f, 0.f, 0.f, 0.f};
    float lsum = 0.f;

    const uint4* hb = (const uint4*)hpB + (size_t)bh * 8192;   // [g][d] in uint4 units

    for (int m0 = 0; m0 < 1024; m0 += 32) {
        float4 d0 = *(const float4*)(edrow + m0 + quad * 8);
        float4 d1 = *(const float4*)(edrow + m0 + quad * 8 + 4);
        float dv[8] = {d0.x, d0.y, d0.z, d0.w, d1.x, d1.y, d1.z, d1.w};
        bf16x8 af;
#pragma unroll
        for (int j = 0; j < 8; ++j) {
            float a1 = fmaf(dv[j], K, s2m);
            float a2 = fmaf(dv[j], K5, s5m);
            float p = __builtin_amdgcn_exp2f(fmaxf(a1, a2));
            lsum += p;
            af[j] = (__bf16)p;
        }
        const int gm = (m0 >> 3) + quad;
#pragma unroll
        for (int ct = 0; ct < 4; ++ct) {
            U16x8 bu; bu.u = hb[gm * 64 + ct * 16 + col];
            acc[ct] = __builtin_amdgcn_mfma_f32_16x16x32_bf16(af, bu.b, acc[ct], 0, 0, 0);
        }
    }

    // softmax denominators: reduce over quads, then fetch per-output-row value
    lsum += __shfl_xor(lsum, 16, 64);
    lsum += __shfl_xor(lsum, 32, 64);
    float inv[4];
#pragma unroll
    for (int r = 0; r < 4; ++r)
        inv[r] = __builtin_amdgcn_rcpf(__shfl(lsum, quad * 4 + r, 16));

    // epilogue: out = elu(acc/l + h)
#pragma unroll
    for (int ct = 0; ct < 4; ++ct) {
#pragma unroll
        for (int r = 0; r < 4; ++r) {
            int n = n0 + quad * 4 + r;
            size_t off = (size_t)(b * 1024 + n) * 128 + hh * 64 + ct * 16 + col;
            float v = acc[ct][r] * inv[r] + hg[off];
            out[off] = v > 0.f ? v : __builtin_amdgcn_exp2f(v * LOG2E) - 1.f;
        }
    }
}

// ---------------------------------------------------------------------------
extern "C" void kernel_launch(void* const* d_in, const int* in_sizes, int n_in,
                              void* d_out, int out_size, void* d_ws, size_t ws_size,
                              hipStream_t stream) {
    const float* h = (const float*)d_in[0];   // (16,1024,128)
    const float* W = (const float*)d_in[1];   // (2,128,64)
    const float* a = (const float*)d_in[2];   // (2,128,1)
    float* out = (float*)d_out;

    unsigned short* hpB = (unsigned short*)d_ws;                    // 4 MB
    float* es  = (float*)((char*)d_ws + (4u << 20));                // 128 KB
    float* ed  = es + 32 * 1024;                                    // 128 KB
    unsigned short* Wp = (unsigned short*)(ed + 32 * 1024);         // 32 KB
    float* acat = (float*)((char*)Wp + 16384 * sizeof(unsigned short));

    gat_prep<<<1, 256, 0, stream>>>(W, a, Wp, acat);
    gat_hp<<<512, 256, 0, stream>>>(h, Wp, acat, hpB, es, ed);
    gat_attn<<<512, 256, 0, stream>>>(h, hpB, es, ed, out);
}

// Round 3
// 86.569 us; speedup vs baseline: 1.8293x; 1.0347x over previous
//
#include <hip/hip_runtime.h>
#include <math.h>

// GAT layer, MFMA + latency-hiding restructure. B=16, N=1024, IN=128, H=2, D=64.
// out = elu( softmax_m(leakyrelu(e_src[n]+e_dst[m])) @ hp + h )
//
// prep (16 blocks): Wp[k/8][c][k%8] bf16 pack, acat.
// gat_hp (512 blocks): hp = h @ Wcat via mfma_16x16x32_bf16 -> hpB k-packed bf16,
//         es/ed fused from fp32 accumulators.
// gat_attn (2048 blocks): block = (bh, 16-row tile); 4 waves split the m-range
//         (256 m each), register-double-buffered chunk loop, P in registers:
//         P = 2^( max(x,0.2x) - M ), M = L(s_n'+dmax') closed-form row max.
//         Partial acc/lsum combined via LDS (stride-17, conflict-free), 1 barrier.

#define LOG2E 1.44269504088896340736f

typedef __bf16 bf16x8 __attribute__((ext_vector_type(8)));
typedef float floatx4 __attribute__((ext_vector_type(4)));

union U16x8 { uint4 u; bf16x8 b; };

__device__ __forceinline__ unsigned short f2bf(float f) {
    union { __bf16 b; unsigned short u; } x;
    x.b = (__bf16)f;
    return x.u;
}

// ---------------------------------------------------------------------------
// prep: pack W to bf16 k-major-8 layout; build acat. 16 blocks x 256.
// ---------------------------------------------------------------------------
__global__ __launch_bounds__(256) void gat_prep(
    const float* __restrict__ Wg,   // (2,128,64)
    const float* __restrict__ ag,   // (2,128)
    unsigned short* __restrict__ Wp,  // (16,128,8) bf16
    float* __restrict__ acat)         // (256)
{
    const int t = threadIdx.x;
    const int base = blockIdx.x * 1024;
#pragma unroll
    for (int i = 0; i < 4; ++i) {
        int idx = base + i * 256 + t;           // 16384 total
        int c = idx & 127, k = idx >> 7;
        float v = Wg[(c >> 6) * 8192 + k * 64 + (c & 63)];
        Wp[((k >> 3) * 128 + c) * 8 + (k & 7)] = f2bf(v);
    }
    if (blockIdx.x == 0 && t < 128) {
        acat[t]       = ag[(t >> 6) * 128 + (t & 63)];
        acat[128 + t] = ag[(t >> 6) * 128 + 64 + (t & 63)];
    }
}

// ---------------------------------------------------------------------------
// Kernel A: hp = h @ Wcat. 512 blocks x 256 thr; wave = (16-row tile, head).
// ---------------------------------------------------------------------------
__global__ __launch_bounds__(256) void gat_hp(
    const float* __restrict__ hg,        // (16384,128)
    const unsigned short* __restrict__ Wp,
    const float* __restrict__ acat,
    unsigned short* __restrict__ hpB,    // (32,128,64,8) bf16
    float* __restrict__ es_g,            // (32,1024)
    float* __restrict__ ed_g)            // (32,1024)
{
    const int t = threadIdx.x;
    const int lane = t & 63;
    const int wv = blockIdx.x * 4 + (t >> 6);   // 0..2047
    const int rt = wv >> 1;                     // global 16-row tile, 0..1023
    const int half = wv & 1;                    // head
    const int n0 = rt * 16;
    const int col = lane & 15, quad = lane >> 4;

    floatx4 acc[4];
#pragma unroll
    for (int ct = 0; ct < 4; ++ct) acc[ct] = (floatx4){0.f, 0.f, 0.f, 0.f};

    const float* hrow = hg + (size_t)(n0 + col) * 128;
    const uint4* wp4 = (const uint4*)Wp;
#pragma unroll
    for (int kq = 0; kq < 4; ++kq) {
        float4 h0 = *(const float4*)(hrow + kq * 32 + quad * 8);
        float4 h1 = *(const float4*)(hrow + kq * 32 + quad * 8 + 4);
        bf16x8 af;
        af[0] = (__bf16)h0.x; af[1] = (__bf16)h0.y;
        af[2] = (__bf16)h0.z; af[3] = (__bf16)h0.w;
        af[4] = (__bf16)h1.x; af[5] = (__bf16)h1.y;
        af[6] = (__bf16)h1.z; af[7] = (__bf16)h1.w;
        const uint4* wbase = wp4 + (size_t)(kq * 4 + quad) * 128 + half * 64;
#pragma unroll
        for (int ct = 0; ct < 4; ++ct) {
            U16x8 bu; bu.u = wbase[ct * 16 + col];
            acc[ct] = __builtin_amdgcn_mfma_f32_16x16x32_bf16(af, bu.b, acc[ct], 0, 0, 0);
        }
    }

    const int b = n0 >> 10;
    const int nloc = n0 & 1023;
    const int bh = b * 2 + half;

    // fused e_src / e_dst from fp32 accumulators
    float esr[4] = {0.f, 0.f, 0.f, 0.f}, edr[4] = {0.f, 0.f, 0.f, 0.f};
#pragma unroll
    for (int ct = 0; ct < 4; ++ct) {
        int c = half * 64 + ct * 16 + col;
        float as = acat[c], ad = acat[128 + c];
#pragma unroll
        for (int r = 0; r < 4; ++r) {
            esr[r] = fmaf(acc[ct][r], as, esr[r]);
            edr[r] = fmaf(acc[ct][r], ad, edr[r]);
        }
    }
#pragma unroll
    for (int off = 1; off <= 8; off <<= 1) {
#pragma unroll
        for (int r = 0; r < 4; ++r) {
            esr[r] += __shfl_xor(esr[r], off, 64);
            edr[r] += __shfl_xor(edr[r], off, 64);
        }
    }
    if (col == 0) {
        size_t base = (size_t)bh * 1024 + nloc + quad * 4;
#pragma unroll
        for (int r = 0; r < 4; ++r) {
            es_g[base + r] = esr[r];
            ed_g[base + r] = edr[r];
        }
    }

    // hpB stores: rows n = n0 + quad*4 + r; n%8 = (quad&1)*4 + r
    const int gloc = (nloc >> 3) + (quad >> 1);
#pragma unroll
    for (int ct = 0; ct < 4; ++ct) {
        int d = ct * 16 + col;
        uint2 pk;
        pk.x = (unsigned)f2bf(acc[ct][0]) | ((unsigned)f2bf(acc[ct][1]) << 16);
        pk.y = (unsigned)f2bf(acc[ct][2]) | ((unsigned)f2bf(acc[ct][3]) << 16);
        size_t idx = ((size_t)(bh * 128 + gloc) * 64 + d) * 8 + (quad & 1) * 4;
        *(uint2*)(hpB + idx) = pk;
    }
}

// ---------------------------------------------------------------------------
// Kernel B: attention. 2048 blocks x 256 thr.
// block = (bh = blk&31, nt = blk>>5); 4 waves split m into 256-wide ranges.
// ---------------------------------------------------------------------------
__global__ __launch_bounds__(256, 4) void gat_attn(
    const float* __restrict__ hg,
    const unsigned short* __restrict__ hpB,
    const float* __restrict__ es_g,
    const float* __restrict__ ed_g,
    float* __restrict__ out)
{
    __shared__ float red[4 * 64 * 17];   // [wave][lane][16 acc + lsum], 17 KB

    const int t = threadIdx.x;
    const int lane = t & 63;
    const int w = t >> 6;
    const int bh = blockIdx.x & 31;      // same-bh blocks -> same XCD
    const int nt = blockIdx.x >> 5;      // 0..63
    const int b = bh >> 1, hh = bh & 1;
    const int n0 = nt * 16;
    const int col = lane & 15, quad = lane >> 4;

    const float* edrow = ed_g + (size_t)bh * 1024;

    // dmax over full row (per-wave, no barrier)
    float mx = -1e30f;
#pragma unroll
    for (int i = 0; i < 4; ++i) {
        float4 v = *(const float4*)(edrow + lane * 16 + i * 4);
        mx = fmaxf(mx, fmaxf(fmaxf(v.x, v.y), fmaxf(v.z, v.w)));
    }
#pragma unroll
    for (int off = 1; off < 64; off <<= 1) mx = fmaxf(mx, __shfl_xor(mx, off, 64));

    const float s2 = es_g[(size_t)bh * 1024 + n0 + col] * LOG2E;
    const float x0 = s2 + mx * LOG2E;
    const float M = fmaxf(x0, 0.2f * x0);        // closed-form row max (log2 dom)
    const float s2m = s2 - M;
    const float s5m = 0.2f * s2 - M;
    const float K = LOG2E, K5 = 0.2f * LOG2E;

    floatx4 acc[4];
#pragma unroll
    for (int ct = 0; ct < 4; ++ct) acc[ct] = (floatx4){0.f, 0.f, 0.f, 0.f};
    float lsum = 0.f;

    const uint4* hb = (const uint4*)hpB + (size_t)bh * 8192;
    const int mbase = w * 256;

    // register double-buffer: preload chunk 0
    float4 d0 = *(const float4*)(edrow + mbase + quad * 8);
    float4 d1 = *(const float4*)(edrow + mbase + quad * 8 + 4);
    int gm = (mbase >> 3) + quad;
    uint4 bu0 = hb[gm * 64 + col];
    uint4 bu1 = hb[gm * 64 + 16 + col];
    uint4 bu2 = hb[gm * 64 + 32 + col];
    uint4 bu3 = hb[gm * 64 + 48 + col];

#pragma unroll
    for (int i = 0; i < 8; ++i) {
        float4 c0 = d0, c1 = d1;
        uint4 cb0 = bu0, cb1 = bu1, cb2 = bu2, cb3 = bu3;
        if (i < 7) {
            int m1 = mbase + (i + 1) * 32;
            d0 = *(const float4*)(edrow + m1 + quad * 8);
            d1 = *(const float4*)(edrow + m1 + quad * 8 + 4);
            gm = (m1 >> 3) + quad;
            bu0 = hb[gm * 64 + col];
            bu1 = hb[gm * 64 + 16 + col];
            bu2 = hb[gm * 64 + 32 + col];
            bu3 = hb[gm * 64 + 48 + col];
        }
        float dv[8] = {c0.x, c0.y, c0.z, c0.w, c1.x, c1.y, c1.z, c1.w};
        bf16x8 af;
#pragma unroll
        for (int j = 0; j < 8; ++j) {
            float a1 = fmaf(dv[j], K, s2m);
            float a2 = fmaf(dv[j], K5, s5m);
            float p = __builtin_amdgcn_exp2f(fmaxf(a1, a2));
            lsum += p;
            af[j] = (__bf16)p;
        }
        U16x8 u0; u0.u = cb0;
        U16x8 u1; u1.u = cb1;
        U16x8 u2; u2.u = cb2;
        U16x8 u3; u3.u = cb3;
        acc[0] = __builtin_amdgcn_mfma_f32_16x16x32_bf16(af, u0.b, acc[0], 0, 0, 0);
        acc[1] = __builtin_amdgcn_mfma_f32_16x16x32_bf16(af, u1.b, acc[1], 0, 0, 0);
        acc[2] = __builtin_amdgcn_mfma_f32_16x16x32_bf16(af, u2.b, acc[2], 0, 0, 0);
        acc[3] = __builtin_amdgcn_mfma_f32_16x16x32_bf16(af, u3.b, acc[3], 0, 0, 0);
    }

    // per-wave row-sum over its m-range (reduce across quads)
    lsum += __shfl_xor(lsum, 16, 64);
    lsum += __shfl_xor(lsum, 32, 64);

    // write partials to LDS (stride 17: conflict-free scalar access)
    float* myred = red + (w * 64 + lane) * 17;
#pragma unroll
    for (int ct = 0; ct < 4; ++ct)
#pragma unroll
        for (int r = 0; r < 4; ++r) myred[ct * 4 + r] = acc[ct][r];
    myred[16] = lsum;
    __syncthreads();

    // wave w combines + finishes output stripe ct = w
    float facc[4] = {0.f, 0.f, 0.f, 0.f};
    float ltot = 0.f;
#pragma unroll
    for (int v = 0; v < 4; ++v) {
        const float* rr = red + (v * 64 + lane) * 17;
#pragma unroll
        for (int r = 0; r < 4; ++r) facc[r] += rr[w * 4 + r];
        ltot += rr[16];
    }
    float inv[4];
#pragma unroll
    for (int r = 0; r < 4; ++r)
        inv[r] = __builtin_amdgcn_rcpf(__shfl(ltot, quad * 4 + r, 16));

    // epilogue: out = elu(facc/l + h) for column stripe w*16+col
#pragma unroll
    for (int r = 0; r < 4; ++r) {
        int n = n0 + quad * 4 + r;
        size_t off = (size_t)(b * 1024 + n) * 128 + hh * 64 + w * 16 + col;
        float v = facc[r] * inv[r] + hg[off];
        out[off] = v > 0.f ? v : __builtin_amdgcn_exp2f(v * LOG2E) - 1.f;
    }
}

// ---------------------------------------------------------------------------
extern "C" void kernel_launch(void* const* d_in, const int* in_sizes, int n_in,
                              void* d_out, int out_size, void* d_ws, size_t ws_size,
                              hipStream_t stream) {
    const float* h = (const float*)d_in[0];   // (16,1024,128)
    const float* W = (const float*)d_in[1];   // (2,128,64)
    const float* a = (const float*)d_in[2];   // (2,128,1)
    float* out = (float*)d_out;

    unsigned short* hpB = (unsigned short*)d_ws;                    // 4 MB
    float* es  = (float*)((char*)d_ws + (4u << 20));                // 128 KB
    float* ed  = es + 32 * 1024;                                    // 128 KB
    unsigned short* Wp = (unsigned short*)(ed + 32 * 1024);         // 32 KB
    float* acat = (float*)((char*)Wp + 16384 * sizeof(unsigned short));

    gat_prep<<<16, 256, 0, stream>>>(W, a, Wp, acat);
    gat_hp<<<512, 256, 0, stream>>>(h, Wp, acat, hpB, es, ed);
    gat_attn<<<2048, 256, 0, stream>>>(h, hpB, es, ed, out);
}